// Round 12
// baseline (4321.994 us; speedup 1.0000x reference)
//
#include <hip/hip_runtime.h>
#include <hip/hip_fp16.h>

#define N 4096
#define KX 3072
#define KZ 128
#define NBT (N / 128)               // 32 tile-rows for the MFMA dist kernel
#define NTRI2 (NBT * (NBT + 1) / 2) // 528 triangular tiles

typedef __attribute__((ext_vector_type(8))) short bf16x8;
typedef __attribute__((ext_vector_type(4))) float f32x4;

// ---------- helpers ----------
__device__ __forceinline__ short f2bf(float f) {  // RTN-even fp32 -> bf16
  unsigned u = __float_as_uint(f);
  u += 0x7fffu + ((u >> 16) & 1u);
  return (short)(u >> 16);
}

__device__ __forceinline__ unsigned umin2(unsigned a, unsigned b) { return a < b ? a : b; }

// DPP-based partial u32-min (within 16-lane rows); CTRL compile-time.
template <int CTRL>
__device__ __forceinline__ unsigned dpp_umin(unsigned x) {
  unsigned y = (unsigned)__builtin_amdgcn_update_dpp(0, (int)x, CTRL, 0xF, 0xF, true);
  return umin2(x, y);
}

// ---------- fp32 -> bf16 conversion (8 elems/thread, grid-stride) ----------
__global__ __launch_bounds__(256) void cvt_bf16_kernel(const float* __restrict__ X,
                                                       short* __restrict__ Xb, int n8) {
  int stride = gridDim.x * 256;
  for (int i = blockIdx.x * 256 + threadIdx.x; i < n8; i += stride) {
    float4 a = *(const float4*)(X + (size_t)i * 8);
    float4 b = *(const float4*)(X + (size_t)i * 8 + 4);
    bf16x8 o;
    o[0] = f2bf(a.x); o[1] = f2bf(a.y); o[2] = f2bf(a.z); o[3] = f2bf(a.w);
    o[4] = f2bf(b.x); o[5] = f2bf(b.y); o[6] = f2bf(b.z); o[7] = f2bf(b.w);
    *(bf16x8*)(Xb + (size_t)i * 8) = o;
  }
}

// ---------- row squared norms (exact fp32) ----------
__global__ __launch_bounds__(256) void sqnorm_kernel(const float* __restrict__ X, int K,
                                                     float* __restrict__ sq) {
  int row = blockIdx.x;
  const float4* xr = (const float4*)(X + (size_t)row * K);
  float s = 0.f;
  int n4 = K >> 2;
  for (int i = threadIdx.x; i < n4; i += 256) {
    float4 v = xr[i];
    s += v.x * v.x + v.y * v.y + v.z * v.z + v.w * v.w;
  }
  for (int off = 32; off > 0; off >>= 1) s += __shfl_down(s, off);
  __shared__ float wsum[4];
  int lane = threadIdx.x & 63, w = threadIdx.x >> 6;
  if (lane == 0) wsum[w] = s;
  __syncthreads();
  if (threadIdx.x == 0) {
    float t = 0.f;
    #pragma unroll
    for (int i = 0; i < 4; ++i) t += wsum[i];
    sq[row] = t;
  }
}

// ---------- MFMA bf16 distance GEMM (round-7 proven) ----------
__global__ __launch_bounds__(256) void dist_mfma_kernel(const short* __restrict__ Xb, int K,
                                                        const float* __restrict__ sq,
                                                        __half* __restrict__ D) {
  int t = blockIdx.x;
  int br = (int)((sqrtf(8.0f * (float)t + 1.0f) - 1.0f) * 0.5f);
  while ((br + 1) * (br + 2) / 2 <= t) ++br;
  while (br * (br + 1) / 2 > t) --br;
  int bc = t - br * (br + 1) / 2;
  int i0 = br * 128, j0 = bc * 128;

  __shared__ short As[128][40];
  __shared__ short Bs[128][40];

  int tid = threadIdx.x, lane = tid & 63, w = tid >> 6;
  int wr = w >> 1, wc = w & 1;
  int fr = lane & 15, fc = lane >> 4;

  f32x4 acc[4][4];
  #pragma unroll
  for (int m = 0; m < 4; ++m)
    #pragma unroll
    for (int nn = 0; nn < 4; ++nn)
      acc[m][nn] = (f32x4){0.f, 0.f, 0.f, 0.f};

  for (int k0 = 0; k0 < K; k0 += 32) {
    #pragma unroll
    for (int u = 0; u < 2; ++u) {
      int f = tid + u * 256;
      int r = f >> 2;
      int c = (f & 3) * 8;
      *(bf16x8*)&As[r][c] = *(const bf16x8*)(Xb + (size_t)(i0 + r) * K + k0 + c);
      *(bf16x8*)&Bs[r][c] = *(const bf16x8*)(Xb + (size_t)(j0 + r) * K + k0 + c);
    }
    __syncthreads();
    bf16x8 af[4], bg[4];
    #pragma unroll
    for (int m = 0; m < 4; ++m)
      af[m] = *(const bf16x8*)&As[wr * 64 + m * 16 + fr][fc * 8];
    #pragma unroll
    for (int nn = 0; nn < 4; ++nn)
      bg[nn] = *(const bf16x8*)&Bs[wc * 64 + nn * 16 + fr][fc * 8];
    #pragma unroll
    for (int m = 0; m < 4; ++m)
      #pragma unroll
      for (int nn = 0; nn < 4; ++nn)
        acc[m][nn] = __builtin_amdgcn_mfma_f32_16x16x32_bf16(af[m], bg[nn], acc[m][nn], 0, 0, 0);
    __syncthreads();
  }

  #pragma unroll
  for (int m = 0; m < 4; ++m) {
    #pragma unroll
    for (int nn = 0; nn < 4; ++nn) {
      int gj = j0 + wc * 64 + nn * 16 + fr;
      float sqj = sq[gj];
      #pragma unroll
      for (int e = 0; e < 4; ++e) {
        int gi = i0 + wr * 64 + m * 16 + fc * 4 + e;
        float d2 = sq[gi] + sqj - 2.0f * acc[m][nn][e];
        float d = sqrtf(fmaxf(d2, 0.0f));
        __half h = __float2half(d);
        D[(size_t)gi * N + gj] = h;
        D[(size_t)gj * N + gi] = h;
      }
    }
  }
}

// ---------- MST: u32-key deferred pipeline + tagged-slot spin sync ----------
// Per-step s_barrier replaced by data sync: each wave writes its minimum as
// u64 {tag=t+1, key} into slot[p][w] (parity double-buffer), then spins until
// all 8 slots of this parity carry tag t+1. Skew is provably <2 steps (a wave
// can't pass step t+1's spin before the slowest wrote t+1), so parity slots
// are never clobbered while needed; stale entries always have smaller tags
// (tags increase monotonically from 0). Fast waves issue their next row load
// early -> jitter absorption instead of lockstep. Deterministic: spin exits on
// data presence; values are timing-independent.
#define INFK(idx) (0xFFFF0000u | (unsigned)(idx))

__global__ __launch_bounds__(512) void mst_kernel(const __half* __restrict__ Dx,
                                                  const __half* __restrict__ Dz,
                                                  int2* __restrict__ ex,
                                                  int2* __restrict__ ez) {
  const __half* __restrict__ D = (blockIdx.x == 0) ? Dx : Dz;
  int2* __restrict__ edges = (blockIdx.x == 0) ? ex : ez;

  int tid = threadIdx.x;      // 0..511
  int lane = tid & 63;
  int w = tid >> 6;           // wave 0..7
  int base = tid * 8;         // nodes [base, base+8)

  unsigned mdk0, mdk1, mdk2, mdk3, mdk4, mdk5, mdk6, mdk7;
  int par0 = 0, par1 = 0, par2 = 0, par3 = 0, par4 = 0, par5 = 0, par6 = 0, par7 = 0;
  {
    uint4 u = *(const uint4*)(D + base);
    mdk0 = (u.x << 16) | (unsigned)(base + 0);
    mdk1 = (u.x & 0xffff0000u) | (unsigned)(base + 1);
    mdk2 = (u.y << 16) | (unsigned)(base + 2);
    mdk3 = (u.y & 0xffff0000u) | (unsigned)(base + 3);
    mdk4 = (u.z << 16) | (unsigned)(base + 4);
    mdk5 = (u.z & 0xffff0000u) | (unsigned)(base + 5);
    mdk6 = (u.w << 16) | (unsigned)(base + 6);
    mdk7 = (u.w & 0xffff0000u) | (unsigned)(base + 7);
  }
  if (tid == 0) mdk0 = INFK(0);  // node 0 starts in tree

  __shared__ unsigned long long slot[2][8];  // {tag<<32 | key}
  __shared__ uint2 eld[N - 1];               // edge buffer (32 KB LDS)

  // ---- prologue: j0 = argmin(initial md); tag 0 everywhere (stale vs tags>=1)
  int j;
  {
    unsigned x = umin2(umin2(umin2(mdk0, mdk1), umin2(mdk2, mdk3)),
                       umin2(umin2(mdk4, mdk5), umin2(mdk6, mdk7)));
    x = dpp_umin<0xB1>(x);   // xor 1
    x = dpp_umin<0x4E>(x);   // xor 2
    x = dpp_umin<0x141>(x);  // xor 4 (row_half_mirror)
    x = dpp_umin<0x140>(x);  // xor 8 (row_mirror)
    unsigned r0 = (unsigned)__builtin_amdgcn_readlane((int)x, 0);
    unsigned r1 = (unsigned)__builtin_amdgcn_readlane((int)x, 16);
    unsigned r2 = (unsigned)__builtin_amdgcn_readlane((int)x, 32);
    unsigned r3 = (unsigned)__builtin_amdgcn_readlane((int)x, 48);
    unsigned wm = umin2(umin2(r0, r1), umin2(r2, r3));
    if (lane == 0) {
      slot[1][w] = (unsigned long long)wm;  // tag 0
      slot[0][w] = 0xFFFFFFFFULL;           // tag 0, key INF
    }
    __syncthreads();
    unsigned k = 0xFFFFFFFFu;
    #pragma unroll
    for (int s = 0; s < 8; ++s) k = umin2(k, (unsigned)slot[1][s]);
    j = (int)(k & 0xFFFu);
  }

  // carried state: previous row keys + its position
  unsigned prk0 = 0xFFFFFFFFu, prk1 = 0xFFFFFFFFu, prk2 = 0xFFFFFFFFu, prk3 = 0xFFFFFFFFu,
           prk4 = 0xFFFFFFFFu, prk5 = 0xFFFFFFFFu, prk6 = 0xFFFFFFFFu, prk7 = 0xFFFFFFFFu;
  int jp = 0, jtprev = -1, jlprev = 0;

  for (int t = 0; t < N - 1; ++t) {
    int p = t & 1;
    unsigned tag = (unsigned)(t + 1);
    int jt = j >> 3, jl = j & 7;

    // 1. issue this step's row load; pin issue order
    uint4 u = *(const uint4*)(D + (size_t)j * N + base);
    __builtin_amdgcn_sched_barrier(0);

    // 2. deferred md/par update with PREVIOUS row (reference step t-1 tail)
    #define DUPD(q) { bool up_ = prk##q < mdk##q; mdk##q = up_ ? prk##q : mdk##q; par##q = up_ ? jp : par##q; }
    DUPD(0) DUPD(1) DUPD(2) DUPD(3) DUPD(4) DUPD(5) DUPD(6) DUPD(7)
    #undef DUPD
    if (jtprev == tid) {   // re-INF at j_{t-1} (after min, like .at[j].set(inf))
      if      (jlprev == 0) mdk0 = INFK(base + 0);
      else if (jlprev == 1) mdk1 = INFK(base + 1);
      else if (jlprev == 2) mdk2 = INFK(base + 2);
      else if (jlprev == 3) mdk3 = INFK(base + 3);
      else if (jlprev == 4) mdk4 = INFK(base + 4);
      else if (jlprev == 5) mdk5 = INFK(base + 5);
      else if (jlprev == 6) mdk6 = INFK(base + 6);
      else                  mdk7 = INFK(base + 7);
    }

    // 3. record edge t into LDS
    if (jt == tid) {
      int pj = (jl == 0) ? par0 : (jl == 1) ? par1 : (jl == 2) ? par2 :
               (jl == 3) ? par3 : (jl == 4) ? par4 : (jl == 5) ? par5 :
               (jl == 6) ? par6 : par7;
      eld[t] = make_uint2((unsigned)pj, (unsigned)j);
    }

    // 4. eager INF at current j
    if (jt == tid) {
      if      (jl == 0) mdk0 = INFK(base + 0);
      else if (jl == 1) mdk1 = INFK(base + 1);
      else if (jl == 2) mdk2 = INFK(base + 2);
      else if (jl == 3) mdk3 = INFK(base + 3);
      else if (jl == 4) mdk4 = INFK(base + 4);
      else if (jl == 5) mdk5 = INFK(base + 5);
      else if (jl == 6) mdk6 = INFK(base + 6);
      else              mdk7 = INFK(base + 7);
    }

    // 5. A-tree over md keys (pure VALU, hidden under load)
    unsigned ak = umin2(umin2(umin2(mdk0, mdk1), umin2(mdk2, mdk3)),
                        umin2(umin2(mdk4, mdk5), umin2(mdk6, mdk7)));

    // 6. B: build fresh row keys (first use of u -> waitcnt lands here)
    prk0 = (u.x << 16) | (unsigned)(base + 0);
    prk1 = (u.x & 0xffff0000u) | (unsigned)(base + 1);
    prk2 = (u.y << 16) | (unsigned)(base + 2);
    prk3 = (u.y & 0xffff0000u) | (unsigned)(base + 3);
    prk4 = (u.z << 16) | (unsigned)(base + 4);
    prk5 = (u.z & 0xffff0000u) | (unsigned)(base + 5);
    prk6 = (u.w << 16) | (unsigned)(base + 6);
    prk7 = (u.w & 0xffff0000u) | (unsigned)(base + 7);
    {
      bool self = (jt == tid);
      unsigned b0 = (self && jl == 0) ? 0xFFFFFFFFu : prk0;
      unsigned b1 = (self && jl == 1) ? 0xFFFFFFFFu : prk1;
      unsigned b2 = (self && jl == 2) ? 0xFFFFFFFFu : prk2;
      unsigned b3 = (self && jl == 3) ? 0xFFFFFFFFu : prk3;
      unsigned b4 = (self && jl == 4) ? 0xFFFFFFFFu : prk4;
      unsigned b5 = (self && jl == 5) ? 0xFFFFFFFFu : prk5;
      unsigned b6 = (self && jl == 6) ? 0xFFFFFFFFu : prk6;
      unsigned b7 = (self && jl == 7) ? 0xFFFFFFFFu : prk7;
      unsigned bk = umin2(umin2(umin2(b0, b1), umin2(b2, b3)),
                          umin2(umin2(b4, b5), umin2(b6, b7)));
      unsigned x = umin2(ak, bk);
      x = dpp_umin<0xB1>(x);
      x = dpp_umin<0x4E>(x);
      x = dpp_umin<0x141>(x);
      x = dpp_umin<0x140>(x);
      unsigned r0 = (unsigned)__builtin_amdgcn_readlane((int)x, 0);
      unsigned r1 = (unsigned)__builtin_amdgcn_readlane((int)x, 16);
      unsigned r2 = (unsigned)__builtin_amdgcn_readlane((int)x, 32);
      unsigned r3 = (unsigned)__builtin_amdgcn_readlane((int)x, 48);
      unsigned wm = umin2(umin2(r0, r1), umin2(r2, r3));
      if (lane == 0)
        slot[p][w] = ((unsigned long long)tag << 32) | (unsigned long long)wm;
    }

    // 7. bookkeeping for the deferred update
    jp = j; jtprev = jt; jlprev = jl;

    // 8. spin until all 8 slots of this parity carry this step's tag
    {
      volatile const unsigned long long* sp = &slot[p][0];
      unsigned key;
      for (;;) {
        unsigned long long s0 = sp[0], s1 = sp[1], s2 = sp[2], s3 = sp[3],
                           s4 = sp[4], s5 = sp[5], s6 = sp[6], s7 = sp[7];
        bool ok = ((unsigned)(s0 >> 32) == tag) & ((unsigned)(s1 >> 32) == tag) &
                  ((unsigned)(s2 >> 32) == tag) & ((unsigned)(s3 >> 32) == tag) &
                  ((unsigned)(s4 >> 32) == tag) & ((unsigned)(s5 >> 32) == tag) &
                  ((unsigned)(s6 >> 32) == tag) & ((unsigned)(s7 >> 32) == tag);
        if (ok) {
          key = umin2(umin2(umin2((unsigned)s0, (unsigned)s1),
                            umin2((unsigned)s2, (unsigned)s3)),
                      umin2(umin2((unsigned)s4, (unsigned)s5),
                            umin2((unsigned)s6, (unsigned)s7)));
          j = (int)(key & 0xFFFu);
          break;
        }
      }
    }
  }

  // ---- dump edges LDS -> global (coalesced)
  __syncthreads();
  for (int e = tid; e < N - 1; e += 512) {
    uint2 v = eld[e];
    edges[e] = make_int2((int)v.x, (int)v.y);
  }
}

// ---------- final loss ----------
__global__ __launch_bounds__(1024) void loss_kernel(const __half* __restrict__ Dx,
                                                    const __half* __restrict__ Dz,
                                                    const int2* __restrict__ ex,
                                                    const int2* __restrict__ ez,
                                                    float* __restrict__ out) {
  int tid = threadIdx.x;
  float s = 0.f;
  const int M = N - 1;
  for (int e = tid; e < 2 * M; e += 1024) {
    int2 uv = (e < M) ? ex[e] : ez[e - M];
    size_t off = (size_t)uv.x * N + uv.y;
    float dx = __half2float(Dx[off]);
    float dz = __half2float(Dz[off]);
    float d = dx - dz;
    s += d * d;
  }
  for (int off = 32; off > 0; off >>= 1) s += __shfl_down(s, off);
  __shared__ float wsum[16];
  int lane = tid & 63, w = tid >> 6;
  if (lane == 0) wsum[w] = s;
  __syncthreads();
  if (tid == 0) {
    float t = 0.f;
    #pragma unroll
    for (int i = 0; i < 16; ++i) t += wsum[i];
    out[0] = 0.5f * t;
  }
}

// ---------- launch ----------
extern "C" void kernel_launch(void* const* d_in, const int* in_sizes, int n_in,
                              void* d_out, int out_size, void* d_ws, size_t ws_size,
                              hipStream_t stream) {
  const float* x = (const float*)d_in[0];
  const float* z = (const float*)d_in[1];
  float* out = (float*)d_out;
  char* ws = (char*)d_ws;

  __half* Dx = (__half*)ws;                       // 32 MB
  __half* Dz = Dx + (size_t)N * N;                // 32 MB
  short* Xb = (short*)(Dz + (size_t)N * N);       // 24 MB
  short* Zb = Xb + (size_t)N * KX;                // 1 MB
  float* sqx = (float*)(Zb + (size_t)N * KZ);
  float* sqz = sqx + N;
  int2* ex = (int2*)(sqz + N);
  int2* ez = ex + (N - 1);

  cvt_bf16_kernel<<<2048, 256, 0, stream>>>(x, Xb, N * KX / 8);
  cvt_bf16_kernel<<<256, 256, 0, stream>>>(z, Zb, N * KZ / 8);
  sqnorm_kernel<<<N, 256, 0, stream>>>(x, KX, sqx);
  sqnorm_kernel<<<N, 256, 0, stream>>>(z, KZ, sqz);
  dist_mfma_kernel<<<NTRI2, 256, 0, stream>>>(Xb, KX, sqx, Dx);
  dist_mfma_kernel<<<NTRI2, 256, 0, stream>>>(Zb, KZ, sqz, Dz);
  mst_kernel<<<2, 512, 0, stream>>>(Dx, Dz, ex, ez);
  loss_kernel<<<1, 1024, 0, stream>>>(Dx, Dz, ex, ez, out);
}

// Round 13
// 2225.420 us; speedup vs baseline: 1.9421x; 1.9421x over previous
//
#include <hip/hip_runtime.h>
#include <hip/hip_fp16.h>

#define N 4096
#define KX 3072
#define KZ 128
#define NBT (N / 128)               // 32 tile-rows for the MFMA dist kernel
#define NTRI2 (NBT * (NBT + 1) / 2) // 528 triangular tiles

typedef __attribute__((ext_vector_type(8))) short bf16x8;
typedef __attribute__((ext_vector_type(4))) float f32x4;

// ---------- helpers ----------
__device__ __forceinline__ short f2bf(float f) {  // RTN-even fp32 -> bf16
  unsigned u = __float_as_uint(f);
  u += 0x7fffu + ((u >> 16) & 1u);
  return (short)(u >> 16);
}

__device__ __forceinline__ unsigned umin2(unsigned a, unsigned b) { return a < b ? a : b; }

// DPP-based partial u32-min (within 16-lane rows); CTRL compile-time.
template <int CTRL>
__device__ __forceinline__ unsigned dpp_umin(unsigned x) {
  unsigned y = (unsigned)__builtin_amdgcn_update_dpp(0, (int)x, CTRL, 0xF, 0xF, true);
  return umin2(x, y);
}

#define INFK(idx) (0xFFFF0000u | (unsigned)(idx))

// ---------- fp32 -> bf16 conversion (8 elems/thread, grid-stride) ----------
__global__ __launch_bounds__(256) void cvt_bf16_kernel(const float* __restrict__ X,
                                                       short* __restrict__ Xb, int n8) {
  int stride = gridDim.x * 256;
  for (int i = blockIdx.x * 256 + threadIdx.x; i < n8; i += stride) {
    float4 a = *(const float4*)(X + (size_t)i * 8);
    float4 b = *(const float4*)(X + (size_t)i * 8 + 4);
    bf16x8 o;
    o[0] = f2bf(a.x); o[1] = f2bf(a.y); o[2] = f2bf(a.z); o[3] = f2bf(a.w);
    o[4] = f2bf(b.x); o[5] = f2bf(b.y); o[6] = f2bf(b.z); o[7] = f2bf(b.w);
    *(bf16x8*)(Xb + (size_t)i * 8) = o;
  }
}

// ---------- row squared norms (exact fp32) ----------
__global__ __launch_bounds__(256) void sqnorm_kernel(const float* __restrict__ X, int K,
                                                     float* __restrict__ sq) {
  int row = blockIdx.x;
  const float4* xr = (const float4*)(X + (size_t)row * K);
  float s = 0.f;
  int n4 = K >> 2;
  for (int i = threadIdx.x; i < n4; i += 256) {
    float4 v = xr[i];
    s += v.x * v.x + v.y * v.y + v.z * v.z + v.w * v.w;
  }
  for (int off = 32; off > 0; off >>= 1) s += __shfl_down(s, off);
  __shared__ float wsum[4];
  int lane = threadIdx.x & 63, w = threadIdx.x >> 6;
  if (lane == 0) wsum[w] = s;
  __syncthreads();
  if (threadIdx.x == 0) {
    float t = 0.f;
    #pragma unroll
    for (int i = 0; i < 4; ++i) t += wsum[i];
    sq[row] = t;
  }
}

// ---------- MFMA bf16 distance GEMM ----------
// KEYS=true: writes u32 argmin keys (halfbits(d)<<16)|col, diagonal = INF-key
// (semantics-preserving: the suppressed self-parent par[j]=j can never reach
// an edge record — resurrection overwrites it before j can be re-selected).
// KEYS=false: writes plain half distances (round-7 proven path).
template <bool KEYS>
__global__ __launch_bounds__(256) void dist_mfma_kernel(const short* __restrict__ Xb, int K,
                                                        const float* __restrict__ sq,
                                                        void* __restrict__ Dout) {
  int t = blockIdx.x;
  int br = (int)((sqrtf(8.0f * (float)t + 1.0f) - 1.0f) * 0.5f);
  while ((br + 1) * (br + 2) / 2 <= t) ++br;
  while (br * (br + 1) / 2 > t) --br;
  int bc = t - br * (br + 1) / 2;
  int i0 = br * 128, j0 = bc * 128;

  __shared__ short As[128][40];
  __shared__ short Bs[128][40];

  int tid = threadIdx.x, lane = tid & 63, w = tid >> 6;
  int wr = w >> 1, wc = w & 1;
  int fr = lane & 15, fc = lane >> 4;

  f32x4 acc[4][4];
  #pragma unroll
  for (int m = 0; m < 4; ++m)
    #pragma unroll
    for (int nn = 0; nn < 4; ++nn)
      acc[m][nn] = (f32x4){0.f, 0.f, 0.f, 0.f};

  for (int k0 = 0; k0 < K; k0 += 32) {
    #pragma unroll
    for (int u = 0; u < 2; ++u) {
      int f = tid + u * 256;
      int r = f >> 2;
      int c = (f & 3) * 8;
      *(bf16x8*)&As[r][c] = *(const bf16x8*)(Xb + (size_t)(i0 + r) * K + k0 + c);
      *(bf16x8*)&Bs[r][c] = *(const bf16x8*)(Xb + (size_t)(j0 + r) * K + k0 + c);
    }
    __syncthreads();
    bf16x8 af[4], bg[4];
    #pragma unroll
    for (int m = 0; m < 4; ++m)
      af[m] = *(const bf16x8*)&As[wr * 64 + m * 16 + fr][fc * 8];
    #pragma unroll
    for (int nn = 0; nn < 4; ++nn)
      bg[nn] = *(const bf16x8*)&Bs[wc * 64 + nn * 16 + fr][fc * 8];
    #pragma unroll
    for (int m = 0; m < 4; ++m)
      #pragma unroll
      for (int nn = 0; nn < 4; ++nn)
        acc[m][nn] = __builtin_amdgcn_mfma_f32_16x16x32_bf16(af[m], bg[nn], acc[m][nn], 0, 0, 0);
    __syncthreads();
  }

  #pragma unroll
  for (int m = 0; m < 4; ++m) {
    #pragma unroll
    for (int nn = 0; nn < 4; ++nn) {
      int gj = j0 + wc * 64 + nn * 16 + fr;
      float sqj = sq[gj];
      #pragma unroll
      for (int e = 0; e < 4; ++e) {
        int gi = i0 + wr * 64 + m * 16 + fc * 4 + e;
        float d2 = sq[gi] + sqj - 2.0f * acc[m][nn][e];
        float d = sqrtf(fmaxf(d2, 0.0f));
        __half h = __float2half(d);
        if constexpr (KEYS) {
          unsigned hb = (unsigned)__half_as_ushort(h);
          unsigned* Kd = (unsigned*)Dout;
          unsigned kij = (gi == gj) ? INFK(gj) : ((hb << 16) | (unsigned)gj);
          unsigned kji = (gi == gj) ? INFK(gi) : ((hb << 16) | (unsigned)gi);
          Kd[(size_t)gi * N + gj] = kij;
          Kd[(size_t)gj * N + gi] = kji;
        } else {
          __half* D = (__half*)Dout;
          D[(size_t)gi * N + gj] = h;
          D[(size_t)gj * N + gi] = h;
        }
      }
    }
  }
}

// ---------- MST on precomputed keys (exact reference semantics) ----------
__global__ __launch_bounds__(512) void mst_keys_kernel(const unsigned* __restrict__ Kx,
                                                       const unsigned* __restrict__ Kz,
                                                       int2* __restrict__ ex,
                                                       int2* __restrict__ ez) {
  const unsigned* __restrict__ Kd = (blockIdx.x == 0) ? Kx : Kz;
  int2* __restrict__ edges = (blockIdx.x == 0) ? ex : ez;

  int tid = threadIdx.x;      // 0..511
  int lane = tid & 63;
  int w = tid >> 6;           // wave 0..7
  int base = tid * 8;         // nodes [base, base+8)

  unsigned mdk0, mdk1, mdk2, mdk3, mdk4, mdk5, mdk6, mdk7;
  int par0 = 0, par1 = 0, par2 = 0, par3 = 0, par4 = 0, par5 = 0, par6 = 0, par7 = 0;
  {
    uint4 a = *(const uint4*)(Kd + base);
    uint4 b = *(const uint4*)(Kd + base + 4);
    mdk0 = a.x; mdk1 = a.y; mdk2 = a.z; mdk3 = a.w;
    mdk4 = b.x; mdk5 = b.y; mdk6 = b.z; mdk7 = b.w;
    // K[0][0] is the stored INF-key -> node 0 starts in tree automatically
  }

  __shared__ unsigned skey[2][8];
  __shared__ uint2 eld[N - 1];   // edge buffer (32 KB LDS)

  // ---- prologue: j0 = argmin(initial md)
  int j;
  {
    unsigned x = umin2(umin2(umin2(mdk0, mdk1), umin2(mdk2, mdk3)),
                       umin2(umin2(mdk4, mdk5), umin2(mdk6, mdk7)));
    x = dpp_umin<0xB1>(x);   // xor 1
    x = dpp_umin<0x4E>(x);   // xor 2
    x = dpp_umin<0x141>(x);  // xor 4 (row_half_mirror)
    x = dpp_umin<0x140>(x);  // xor 8 (row_mirror)
    unsigned r0 = (unsigned)__builtin_amdgcn_readlane((int)x, 0);
    unsigned r1 = (unsigned)__builtin_amdgcn_readlane((int)x, 16);
    unsigned r2 = (unsigned)__builtin_amdgcn_readlane((int)x, 32);
    unsigned r3 = (unsigned)__builtin_amdgcn_readlane((int)x, 48);
    unsigned wm = umin2(umin2(r0, r1), umin2(r2, r3));
    if (lane == 0) skey[1][w] = wm;
    __syncthreads();
    uint4 A = ((const uint4*)&skey[1][0])[0];
    uint4 B = ((const uint4*)&skey[1][0])[1];
    unsigned k = umin2(umin2(umin2(A.x, A.y), umin2(A.z, A.w)),
                       umin2(umin2(B.x, B.y), umin2(B.z, B.w)));
    j = (int)(k & 0xFFFFu);
  }

  // carried state: previous row keys + its position
  unsigned prk0 = 0xFFFFFFFFu, prk1 = 0xFFFFFFFFu, prk2 = 0xFFFFFFFFu, prk3 = 0xFFFFFFFFu,
           prk4 = 0xFFFFFFFFu, prk5 = 0xFFFFFFFFu, prk6 = 0xFFFFFFFFu, prk7 = 0xFFFFFFFFu;
  int jp = 0, jtprev = -1, jlprev = 0;

  for (int t = 0; t < N - 1; ++t) {
    int p = t & 1;
    int jt = j >> 3, jl = j & 7;

    // 1. issue this step's row load (keys, 32B/thread); pin issue order
    const unsigned* row = Kd + (size_t)j * N + base;
    uint4 ua = *(const uint4*)row;
    uint4 ub = *(const uint4*)(row + 4);
    __builtin_amdgcn_sched_barrier(0);

    // 2. deferred md/par update with PREVIOUS row (reference step t-1 tail)
    #define DUPD(q) { bool up_ = prk##q < mdk##q; mdk##q = up_ ? prk##q : mdk##q; par##q = up_ ? jp : par##q; }
    DUPD(0) DUPD(1) DUPD(2) DUPD(3) DUPD(4) DUPD(5) DUPD(6) DUPD(7)
    #undef DUPD
    if (jtprev == tid) {   // re-INF at j_{t-1} (after min, like .at[j].set(inf))
      if      (jlprev == 0) mdk0 = INFK(base + 0);
      else if (jlprev == 1) mdk1 = INFK(base + 1);
      else if (jlprev == 2) mdk2 = INFK(base + 2);
      else if (jlprev == 3) mdk3 = INFK(base + 3);
      else if (jlprev == 4) mdk4 = INFK(base + 4);
      else if (jlprev == 5) mdk5 = INFK(base + 5);
      else if (jlprev == 6) mdk6 = INFK(base + 6);
      else                  mdk7 = INFK(base + 7);
    }

    // 3. record edge t into LDS
    if (jt == tid) {
      int pj = (jl == 0) ? par0 : (jl == 1) ? par1 : (jl == 2) ? par2 :
               (jl == 3) ? par3 : (jl == 4) ? par4 : (jl == 5) ? par5 :
               (jl == 6) ? par6 : par7;
      eld[t] = make_uint2((unsigned)pj, (unsigned)j);
    }

    // 4. eager INF at current j
    if (jt == tid) {
      if      (jl == 0) mdk0 = INFK(base + 0);
      else if (jl == 1) mdk1 = INFK(base + 1);
      else if (jl == 2) mdk2 = INFK(base + 2);
      else if (jl == 3) mdk3 = INFK(base + 3);
      else if (jl == 4) mdk4 = INFK(base + 4);
      else if (jl == 5) mdk5 = INFK(base + 5);
      else if (jl == 6) mdk6 = INFK(base + 6);
      else              mdk7 = INFK(base + 7);
    }

    // 5. A-tree over md keys (pure VALU, hidden under load)
    unsigned ak = umin2(umin2(umin2(mdk0, mdk1), umin2(mdk2, mdk3)),
                        umin2(umin2(mdk4, mdk5), umin2(mdk6, mdk7)));

    // 6. B-tree directly on loaded keys (no building, no masking —
    //    diagonal is the stored INF-key). First use of ua/ub waits here.
    {
      unsigned bk = umin2(umin2(umin2(ua.x, ua.y), umin2(ua.z, ua.w)),
                          umin2(umin2(ub.x, ub.y), umin2(ub.z, ub.w)));
      unsigned x = umin2(ak, bk);
      x = dpp_umin<0xB1>(x);
      x = dpp_umin<0x4E>(x);
      x = dpp_umin<0x141>(x);
      x = dpp_umin<0x140>(x);
      unsigned r0 = (unsigned)__builtin_amdgcn_readlane((int)x, 0);
      unsigned r1 = (unsigned)__builtin_amdgcn_readlane((int)x, 16);
      unsigned r2 = (unsigned)__builtin_amdgcn_readlane((int)x, 32);
      unsigned r3 = (unsigned)__builtin_amdgcn_readlane((int)x, 48);
      unsigned wm = umin2(umin2(r0, r1), umin2(r2, r3));
      if (lane == 0) skey[p][w] = wm;
    }

    // 7. carry row keys for next step's deferred update
    prk0 = ua.x; prk1 = ua.y; prk2 = ua.z; prk3 = ua.w;
    prk4 = ub.x; prk5 = ub.y; prk6 = ub.z; prk7 = ub.w;
    jp = j; jtprev = jt; jlprev = jl;

    // 8. single barrier; 8-slot u32 combine
    __syncthreads();
    uint4 A = ((const uint4*)&skey[p][0])[0];
    uint4 B = ((const uint4*)&skey[p][0])[1];
    unsigned k = umin2(umin2(umin2(A.x, A.y), umin2(A.z, A.w)),
                       umin2(umin2(B.x, B.y), umin2(B.z, B.w)));
    j = (int)(k & 0xFFFFu);
  }

  // ---- dump edges LDS -> global (coalesced)
  __syncthreads();
  for (int e = tid; e < N - 1; e += 512) {
    uint2 v = eld[e];
    edges[e] = make_int2((int)v.x, (int)v.y);
  }
}

// ---------- MST on half distances (round-10 proven fallback) ----------
__global__ __launch_bounds__(512) void mst_half_kernel(const __half* __restrict__ Dx,
                                                       const __half* __restrict__ Dz,
                                                       int2* __restrict__ ex,
                                                       int2* __restrict__ ez) {
  const __half* __restrict__ D = (blockIdx.x == 0) ? Dx : Dz;
  int2* __restrict__ edges = (blockIdx.x == 0) ? ex : ez;

  int tid = threadIdx.x;
  int lane = tid & 63;
  int w = tid >> 6;
  int base = tid * 8;

  unsigned mdk0, mdk1, mdk2, mdk3, mdk4, mdk5, mdk6, mdk7;
  int par0 = 0, par1 = 0, par2 = 0, par3 = 0, par4 = 0, par5 = 0, par6 = 0, par7 = 0;
  {
    uint4 u = *(const uint4*)(D + base);
    mdk0 = (u.x << 16) | (unsigned)(base + 0);
    mdk1 = (u.x & 0xffff0000u) | (unsigned)(base + 1);
    mdk2 = (u.y << 16) | (unsigned)(base + 2);
    mdk3 = (u.y & 0xffff0000u) | (unsigned)(base + 3);
    mdk4 = (u.z << 16) | (unsigned)(base + 4);
    mdk5 = (u.z & 0xffff0000u) | (unsigned)(base + 5);
    mdk6 = (u.w << 16) | (unsigned)(base + 6);
    mdk7 = (u.w & 0xffff0000u) | (unsigned)(base + 7);
  }
  if (tid == 0) mdk0 = INFK(0);

  __shared__ unsigned skey[2][8];
  __shared__ uint2 eld[N - 1];

  int j;
  {
    unsigned x = umin2(umin2(umin2(mdk0, mdk1), umin2(mdk2, mdk3)),
                       umin2(umin2(mdk4, mdk5), umin2(mdk6, mdk7)));
    x = dpp_umin<0xB1>(x);
    x = dpp_umin<0x4E>(x);
    x = dpp_umin<0x141>(x);
    x = dpp_umin<0x140>(x);
    unsigned r0 = (unsigned)__builtin_amdgcn_readlane((int)x, 0);
    unsigned r1 = (unsigned)__builtin_amdgcn_readlane((int)x, 16);
    unsigned r2 = (unsigned)__builtin_amdgcn_readlane((int)x, 32);
    unsigned r3 = (unsigned)__builtin_amdgcn_readlane((int)x, 48);
    unsigned wm = umin2(umin2(r0, r1), umin2(r2, r3));
    if (lane == 0) skey[1][w] = wm;
    __syncthreads();
    uint4 A = ((const uint4*)&skey[1][0])[0];
    uint4 B = ((const uint4*)&skey[1][0])[1];
    unsigned k = umin2(umin2(umin2(A.x, A.y), umin2(A.z, A.w)),
                       umin2(umin2(B.x, B.y), umin2(B.z, B.w)));
    j = (int)(k & 0xFFFFu);
  }

  unsigned prk0 = 0xFFFFFFFFu, prk1 = 0xFFFFFFFFu, prk2 = 0xFFFFFFFFu, prk3 = 0xFFFFFFFFu,
           prk4 = 0xFFFFFFFFu, prk5 = 0xFFFFFFFFu, prk6 = 0xFFFFFFFFu, prk7 = 0xFFFFFFFFu;
  int jp = 0, jtprev = -1, jlprev = 0;

  for (int t = 0; t < N - 1; ++t) {
    int p = t & 1;
    int jt = j >> 3, jl = j & 7;

    uint4 u = *(const uint4*)(D + (size_t)j * N + base);
    __builtin_amdgcn_sched_barrier(0);

    #define DUPD(q) { bool up_ = prk##q < mdk##q; mdk##q = up_ ? prk##q : mdk##q; par##q = up_ ? jp : par##q; }
    DUPD(0) DUPD(1) DUPD(2) DUPD(3) DUPD(4) DUPD(5) DUPD(6) DUPD(7)
    #undef DUPD
    if (jtprev == tid) {
      if      (jlprev == 0) mdk0 = INFK(base + 0);
      else if (jlprev == 1) mdk1 = INFK(base + 1);
      else if (jlprev == 2) mdk2 = INFK(base + 2);
      else if (jlprev == 3) mdk3 = INFK(base + 3);
      else if (jlprev == 4) mdk4 = INFK(base + 4);
      else if (jlprev == 5) mdk5 = INFK(base + 5);
      else if (jlprev == 6) mdk6 = INFK(base + 6);
      else                  mdk7 = INFK(base + 7);
    }

    if (jt == tid) {
      int pj = (jl == 0) ? par0 : (jl == 1) ? par1 : (jl == 2) ? par2 :
               (jl == 3) ? par3 : (jl == 4) ? par4 : (jl == 5) ? par5 :
               (jl == 6) ? par6 : par7;
      eld[t] = make_uint2((unsigned)pj, (unsigned)j);
    }

    if (jt == tid) {
      if      (jl == 0) mdk0 = INFK(base + 0);
      else if (jl == 1) mdk1 = INFK(base + 1);
      else if (jl == 2) mdk2 = INFK(base + 2);
      else if (jl == 3) mdk3 = INFK(base + 3);
      else if (jl == 4) mdk4 = INFK(base + 4);
      else if (jl == 5) mdk5 = INFK(base + 5);
      else if (jl == 6) mdk6 = INFK(base + 6);
      else              mdk7 = INFK(base + 7);
    }

    unsigned ak = umin2(umin2(umin2(mdk0, mdk1), umin2(mdk2, mdk3)),
                        umin2(umin2(mdk4, mdk5), umin2(mdk6, mdk7)));

    prk0 = (u.x << 16) | (unsigned)(base + 0);
    prk1 = (u.x & 0xffff0000u) | (unsigned)(base + 1);
    prk2 = (u.y << 16) | (unsigned)(base + 2);
    prk3 = (u.y & 0xffff0000u) | (unsigned)(base + 3);
    prk4 = (u.z << 16) | (unsigned)(base + 4);
    prk5 = (u.z & 0xffff0000u) | (unsigned)(base + 5);
    prk6 = (u.w << 16) | (unsigned)(base + 6);
    prk7 = (u.w & 0xffff0000u) | (unsigned)(base + 7);
    {
      bool self = (jt == tid);
      unsigned b0 = (self && jl == 0) ? 0xFFFFFFFFu : prk0;
      unsigned b1 = (self && jl == 1) ? 0xFFFFFFFFu : prk1;
      unsigned b2 = (self && jl == 2) ? 0xFFFFFFFFu : prk2;
      unsigned b3 = (self && jl == 3) ? 0xFFFFFFFFu : prk3;
      unsigned b4 = (self && jl == 4) ? 0xFFFFFFFFu : prk4;
      unsigned b5 = (self && jl == 5) ? 0xFFFFFFFFu : prk5;
      unsigned b6 = (self && jl == 6) ? 0xFFFFFFFFu : prk6;
      unsigned b7 = (self && jl == 7) ? 0xFFFFFFFFu : prk7;
      unsigned bk = umin2(umin2(umin2(b0, b1), umin2(b2, b3)),
                          umin2(umin2(b4, b5), umin2(b6, b7)));
      unsigned x = umin2(ak, bk);
      x = dpp_umin<0xB1>(x);
      x = dpp_umin<0x4E>(x);
      x = dpp_umin<0x141>(x);
      x = dpp_umin<0x140>(x);
      unsigned r0 = (unsigned)__builtin_amdgcn_readlane((int)x, 0);
      unsigned r1 = (unsigned)__builtin_amdgcn_readlane((int)x, 16);
      unsigned r2 = (unsigned)__builtin_amdgcn_readlane((int)x, 32);
      unsigned r3 = (unsigned)__builtin_amdgcn_readlane((int)x, 48);
      unsigned wm = umin2(umin2(r0, r1), umin2(r2, r3));
      if (lane == 0) skey[p][w] = wm;
    }

    jp = j; jtprev = jt; jlprev = jl;

    __syncthreads();
    uint4 A = ((const uint4*)&skey[p][0])[0];
    uint4 B = ((const uint4*)&skey[p][0])[1];
    unsigned k = umin2(umin2(umin2(A.x, A.y), umin2(A.z, A.w)),
                       umin2(umin2(B.x, B.y), umin2(B.z, B.w)));
    j = (int)(k & 0xFFFFu);
  }

  __syncthreads();
  for (int e = tid; e < N - 1; e += 512) {
    uint2 v = eld[e];
    edges[e] = make_int2((int)v.x, (int)v.y);
  }
}

// ---------- final loss (KEYS=true reads u32 key matrices, else half) ----------
template <bool KEYS>
__global__ __launch_bounds__(1024) void loss_kernel(const void* __restrict__ DxV,
                                                    const void* __restrict__ DzV,
                                                    const int2* __restrict__ ex,
                                                    const int2* __restrict__ ez,
                                                    float* __restrict__ out) {
  int tid = threadIdx.x;
  float s = 0.f;
  const int M = N - 1;
  for (int e = tid; e < 2 * M; e += 1024) {
    int2 uv = (e < M) ? ex[e] : ez[e - M];
    size_t off = (size_t)uv.x * N + uv.y;
    float dx, dz;
    if constexpr (KEYS) {
      dx = __half2float(__ushort_as_half((unsigned short)(((const unsigned*)DxV)[off] >> 16)));
      dz = __half2float(__ushort_as_half((unsigned short)(((const unsigned*)DzV)[off] >> 16)));
    } else {
      dx = __half2float(((const __half*)DxV)[off]);
      dz = __half2float(((const __half*)DzV)[off]);
    }
    float d = dx - dz;
    s += d * d;
  }
  for (int off = 32; off > 0; off >>= 1) s += __shfl_down(s, off);
  __shared__ float wsum[16];
  int lane = tid & 63, w = tid >> 6;
  if (lane == 0) wsum[w] = s;
  __syncthreads();
  if (tid == 0) {
    float t = 0.f;
    #pragma unroll
    for (int i = 0; i < 16; ++i) t += wsum[i];
    out[0] = 0.5f * t;
  }
}

// ---------- launch ----------
extern "C" void kernel_launch(void* const* d_in, const int* in_sizes, int n_in,
                              void* d_out, int out_size, void* d_ws, size_t ws_size,
                              hipStream_t stream) {
  const float* x = (const float*)d_in[0];
  const float* z = (const float*)d_in[1];
  float* out = (float*)d_out;
  char* ws = (char*)d_ws;

  size_t need_keys = (size_t)2 * N * N * 4        // key matrices
                   + (size_t)N * KX * 2 + (size_t)N * KZ * 2  // bf16 inputs
                   + (size_t)2 * N * 4            // sqnorms
                   + (size_t)2 * (N - 1) * 8;     // edges

  if (ws_size >= need_keys) {
    unsigned* Kx = (unsigned*)ws;                   // 64 MB
    unsigned* Kz = Kx + (size_t)N * N;              // 64 MB
    short* Xb = (short*)(Kz + (size_t)N * N);       // 24 MB
    short* Zb = Xb + (size_t)N * KX;                // 1 MB
    float* sqx = (float*)(Zb + (size_t)N * KZ);
    float* sqz = sqx + N;
    int2* ex = (int2*)(sqz + N);
    int2* ez = ex + (N - 1);

    cvt_bf16_kernel<<<2048, 256, 0, stream>>>(x, Xb, N * KX / 8);
    cvt_bf16_kernel<<<256, 256, 0, stream>>>(z, Zb, N * KZ / 8);
    sqnorm_kernel<<<N, 256, 0, stream>>>(x, KX, sqx);
    sqnorm_kernel<<<N, 256, 0, stream>>>(z, KZ, sqz);
    dist_mfma_kernel<true><<<NTRI2, 256, 0, stream>>>(Xb, KX, sqx, Kx);
    dist_mfma_kernel<true><<<NTRI2, 256, 0, stream>>>(Zb, KZ, sqz, Kz);
    mst_keys_kernel<<<2, 512, 0, stream>>>(Kx, Kz, ex, ez);
    loss_kernel<true><<<1, 1024, 0, stream>>>(Kx, Kz, ex, ez, out);
  } else {
    __half* Dx = (__half*)ws;                       // 32 MB
    __half* Dz = Dx + (size_t)N * N;                // 32 MB
    short* Xb = (short*)(Dz + (size_t)N * N);       // 24 MB
    short* Zb = Xb + (size_t)N * KX;                // 1 MB
    float* sqx = (float*)(Zb + (size_t)N * KZ);
    float* sqz = sqx + N;
    int2* ex = (int2*)(sqz + N);
    int2* ez = ex + (N - 1);

    cvt_bf16_kernel<<<2048, 256, 0, stream>>>(x, Xb, N * KX / 8);
    cvt_bf16_kernel<<<256, 256, 0, stream>>>(z, Zb, N * KZ / 8);
    sqnorm_kernel<<<N, 256, 0, stream>>>(x, KX, sqx);
    sqnorm_kernel<<<N, 256, 0, stream>>>(z, KZ, sqz);
    dist_mfma_kernel<false><<<NTRI2, 256, 0, stream>>>(Xb, KX, sqx, Dx);
    dist_mfma_kernel<false><<<NTRI2, 256, 0, stream>>>(Zb, KZ, sqz, Dz);
    mst_half_kernel<<<2, 512, 0, stream>>>(Dx, Dz, ex, ez);
    loss_kernel<false><<<1, 1024, 0, stream>>>(Dx, Dz, ex, ez, out);
  }
}